// Round 4
// baseline (56.796 us; speedup 1.0000x reference)
//
#include <hip/hip_runtime.h>
#include <cstdint>
#include <math.h>

#define NPARTS 4
#define NPTS   8192

// chamfer tiling
#define TPB    256
#define RX     8          // rows per thread (registers)
#define RY     8          // cols per thread (LDS chunk)
#define XB     256        // rows per block = 32*RX
#define YCHUNK 64         // cols per LDS chunk = 8*RY
#define YSEG   512        // cols per block  (8 chunks)
#define YSPLIT 16         // NPTS / YSEG
#define XT     32         // NPTS / XB

// ws layout (bytes)
#define WS_T_OFF      0                          // float[4][16]
#define WS_SUMS_OFF   256                        // double[10]: [p][dir] x8, dist
#define WS_CADT_OFF   512                        // float4[4][8192]  (x,y,z,|x|^2)
#define WS_CAMP_OFF   (WS_CADT_OFF + 524288)     // float[4][4][8192] planes (-2cx,-2cy,-2cz,|c|^2)
#define WS_ROWMIN_OFF (WS_CAMP_OFF + 524288)     // float[4][16][8192]
#define WS_COLMIN_OFF (WS_ROWMIN_OFF + 2097152)  // float[4][32][8192]

typedef float f32x2 __attribute__((ext_vector_type(2)));
typedef float f32x4 __attribute__((ext_vector_type(4)));

__device__ __forceinline__ f32x2 pk_fma(f32x2 a, f32x2 b, f32x2 c) {
    f32x2 d;
    asm("v_pk_fma_f32 %0, %1, %2, %3" : "=v"(d) : "v"(a), "v"(b), "v"(c));
    return d;
}
__device__ __forceinline__ float min3f(float a, float b, float c) {
    float d;
    asm("v_min3_f32 %0, %1, %2, %3" : "=v"(d) : "v"(a), "v"(b), "v"(c));
    return d;
}

__global__ __launch_bounds__(256) void k_setup(const float* __restrict__ rot_quats,
                                               const float* __restrict__ tras,
                                               float* __restrict__ ws,
                                               float* __restrict__ out) {
    if (threadIdx.x < NPARTS) {
        int p = threadIdx.x;
        float q0 = rot_quats[p*4+0], q1 = rot_quats[p*4+1];
        float q2 = rot_quats[p*4+2], q3 = rot_quats[p*4+3];
        float inv = 1.0f / sqrtf(q0*q0 + q1*q1 + q2*q2 + q3*q3);
        float a = q0*inv, b = q1*inv, c = q2*inv, d = q3*inv;
        float T[16];
        T[0]  = 1.f - 2.f*c*c - 2.f*d*d;
        T[1]  = 2.f*b*c - 2.f*a*d;
        T[2]  = 2.f*a*c + 2.f*b*d;
        T[3]  = tras[p*3+0];
        T[4]  = 2.f*b*c + 2.f*a*d;
        T[5]  = 1.f - 2.f*b*b - 2.f*d*d;
        T[6]  = 2.f*c*d - 2.f*a*b;
        T[7]  = tras[p*3+1];
        T[8]  = 2.f*b*d - 2.f*a*c;
        T[9]  = 2.f*a*b + 2.f*c*d;
        T[10] = 1.f - 2.f*b*b - 2.f*c*c;
        T[11] = tras[p*3+2];
        T[12] = 0.f; T[13] = 0.f; T[14] = 0.f; T[15] = 1.f;
        #pragma unroll
        for (int i = 0; i < 16; ++i) {
            ws[p*16 + i] = T[i];
            out[6 + p*16 + i] = T[i];   // transforms output
        }
    }
}

// pre-pass: transform cad, build point buffers, paired-distance sum for E_kin
__global__ __launch_bounds__(256) void k_pre(const float* __restrict__ cam,
                                             const float* __restrict__ cad,
                                             float* __restrict__ ws) {
    int gid = blockIdx.x * 256 + threadIdx.x;   // 0..32767
    int p = gid >> 13;
    int i = gid & (NPTS - 1);
    const float* T = ws + p*16;
    float v0 = cad[(size_t)gid*3+0], v1 = cad[(size_t)gid*3+1], v2 = cad[(size_t)gid*3+2];
    float w0 = fmaf(T[0],v0, fmaf(T[1],v1, fmaf(T[2],v2, T[3])));
    float w1 = fmaf(T[4],v0, fmaf(T[5],v1, fmaf(T[6],v2, T[7])));
    float w2 = fmaf(T[8],v0, fmaf(T[9],v1, fmaf(T[10],v2, T[11])));
    f32x4* cadT = (f32x4*)((char*)ws + WS_CADT_OFF);
    cadT[gid] = (f32x4){w0, w1, w2, w0*w0 + w1*w1 + w2*w2};

    float c0 = cam[(size_t)gid*3+0], c1 = cam[(size_t)gid*3+1], c2 = cam[(size_t)gid*3+2];
    float* camP = (float*)((char*)ws + WS_CAMP_OFF) + (size_t)p*4*NPTS;
    camP[0*NPTS + i] = -2.f*c0;
    camP[1*NPTS + i] = -2.f*c1;
    camP[2*NPTS + i] = -2.f*c2;
    camP[3*NPTS + i] = c0*c0 + c1*c1 + c2*c2;

    float d0 = w0 - c0, d1 = w1 - c1, d2 = w2 - c2;
    double local = sqrt((double)(d0*d0 + d1*d1 + d2*d2));
    __shared__ double red[256];
    red[threadIdx.x] = local;
    __syncthreads();
    for (int s = 128; s > 0; s >>= 1) {
        if (threadIdx.x < s) red[threadIdx.x] += red[threadIdx.x + s];
        __syncthreads();
    }
    if (threadIdx.x == 0) {
        double* dist_sum = (double*)((char*)ws + WS_SUMS_OFF) + 8;
        atomicAdd(dist_sum, red[0]);
    }
}

// Chamfer: ONE pass over d2 matrix per part, row-mins and col-mins fused.
// grid = 4 parts x 32 xtiles x 16 ysplits = 2048 blocks, 256 threads.
// t = x.(-2y) + |y|^2 (rowmin folds t, xsq deferred); u = t + |x|^2 (colmin).
__global__ __launch_bounds__(TPB, 4) void k_chamfer(float* __restrict__ ws) {
    const int tid = threadIdx.x;
    const int tx = tid & 31, ty = tid >> 5;
    const int b = blockIdx.x;
    const int ysi = b & (YSPLIT - 1);
    const int xt  = (b >> 4) & (XT - 1);
    const int p   = b >> 9;

    const f32x4* cadT = (const f32x4*)((char*)ws + WS_CADT_OFF) + (size_t)p*NPTS;
    const float* camP = (const float*)((char*)ws + WS_CAMP_OFF) + (size_t)p*4*NPTS;
    float* rowming = (float*)((char*)ws + WS_ROWMIN_OFF) + ((size_t)(p*YSPLIT + ysi))*NPTS + xt*XB;
    float* colming = (float*)((char*)ws + WS_COLMIN_OFF) + ((size_t)(p*XT + xt))*NPTS;

    __shared__ f32x4 yp4[4][YCHUNK/4];   // SoA planes: 1 KiB
    __shared__ float scr[XB*9];          // transpose-reduce scratch (2304 f)

    // x registers: RX rows, packed broadcast for pk_fma
    f32x2 X0[RX], X1[RX], X2[RX];
    float XS[RX];
    #pragma unroll
    for (int r = 0; r < RX; ++r) {
        f32x4 v = cadT[xt*XB + r*32 + tx];
        X0[r] = (f32x2){v.x, v.x};
        X1[r] = (f32x2){v.y, v.y};
        X2[r] = (f32x2){v.z, v.z};
        XS[r] = v.w;
    }
    float rm[RX];
    #pragma unroll
    for (int r = 0; r < RX; ++r) rm[r] = INFINITY;

    for (int chunk = 0; chunk < YSEG/YCHUNK; ++chunk) {
        const int ybase = ysi*YSEG + chunk*YCHUNK;
        if (tid < 64) {
            int plane = tid >> 4, idx = tid & 15;
            yp4[plane][idx] = *(const f32x4*)(camP + (size_t)plane*NPTS + ybase + idx*4);
        }
        __syncthreads();

        float cmf[RY];
        #pragma unroll
        for (int k = 0; k < RY; ++k) cmf[k] = INFINITY;

        #pragma unroll
        for (int g = 0; g < 2; ++g) {
            int ys4 = ty*2 + g;          // float4 index: covers y = ty*8 + g*4 ..+3
            f32x4 c0 = yp4[0][ys4];
            f32x4 c1 = yp4[1][ys4];
            f32x4 c2 = yp4[2][ys4];
            f32x4 qq = yp4[3][ys4];
            f32x2 c0lo = __builtin_shufflevector(c0, c0, 0,1), c0hi = __builtin_shufflevector(c0, c0, 2,3);
            f32x2 c1lo = __builtin_shufflevector(c1, c1, 0,1), c1hi = __builtin_shufflevector(c1, c1, 2,3);
            f32x2 c2lo = __builtin_shufflevector(c2, c2, 0,1), c2hi = __builtin_shufflevector(c2, c2, 2,3);
            f32x2 qqlo = __builtin_shufflevector(qq, qq, 0,1), qqhi = __builtin_shufflevector(qq, qq, 2,3);
            #pragma unroll
            for (int r = 0; r < RX; r += 2) {
                f32x2 ta = pk_fma(X0[r],   c0lo, qqlo); ta = pk_fma(X1[r],   c1lo, ta); ta = pk_fma(X2[r],   c2lo, ta);
                f32x2 tb = pk_fma(X0[r+1], c0lo, qqlo); tb = pk_fma(X1[r+1], c1lo, tb); tb = pk_fma(X2[r+1], c2lo, tb);
                rm[r]   = min3f(rm[r],   ta.x, ta.y);
                rm[r+1] = min3f(rm[r+1], tb.x, tb.y);
                cmf[g*4+0] = min3f(cmf[g*4+0], ta.x + XS[r], tb.x + XS[r+1]);
                cmf[g*4+1] = min3f(cmf[g*4+1], ta.y + XS[r], tb.y + XS[r+1]);
                f32x2 ua = pk_fma(X0[r],   c0hi, qqhi); ua = pk_fma(X1[r],   c1hi, ua); ua = pk_fma(X2[r],   c2hi, ua);
                f32x2 ub = pk_fma(X0[r+1], c0hi, qqhi); ub = pk_fma(X1[r+1], c1hi, ub); ub = pk_fma(X2[r+1], c2hi, ub);
                rm[r]   = min3f(rm[r],   ua.x, ua.y);
                rm[r+1] = min3f(rm[r+1], ub.x, ub.y);
                cmf[g*4+2] = min3f(cmf[g*4+2], ua.x + XS[r], ub.x + XS[r+1]);
                cmf[g*4+3] = min3f(cmf[g*4+3], ua.y + XS[r], ub.y + XS[r+1]);
            }
        }

        // col-min flush: transpose-reduce over the 32 tx groups
        #pragma unroll
        for (int k = 0; k < RY; ++k) scr[(ty*8+k)*33 + tx] = cmf[k];
        __syncthreads();
        if (tid < YCHUNK) {
            float m = INFINITY;
            #pragma unroll
            for (int j = 0; j < 32; ++j) m = fminf(m, scr[tid*33 + j]);
            colming[ybase + tid] = m;
        }
        __syncthreads();
    }

    // row-min flush: transpose-reduce over the 8 ty groups
    #pragma unroll
    for (int r = 0; r < RX; ++r) scr[(r*32+tx)*9 + ty] = rm[r];
    __syncthreads();
    {
        float m = INFINITY;
        #pragma unroll
        for (int t = 0; t < 8; ++t) m = fminf(m, scr[tid*9 + t]);
        rowming[tid] = m;
    }
}

// combine partials -> per-(part,dir) sum of sqrt(d2)
__global__ __launch_bounds__(256) void k_reduce(float* __restrict__ ws) {
    __shared__ double red[256];
    double local = 0.0;
    const int b = blockIdx.x;
    const int tid = threadIdx.x;
    if (b < 32) {
        int p = b >> 3, seg = b & 7;
        const float* rowmin = (const float*)((const char*)ws + WS_ROWMIN_OFF) + (size_t)p*YSPLIT*NPTS;
        const f32x4* cadT = (const f32x4*)((const char*)ws + WS_CADT_OFF) + (size_t)p*NPTS;
        for (int k = 0; k < 4; ++k) {
            int row = seg*1024 + k*256 + tid;
            float m = INFINITY;
            #pragma unroll
            for (int ysi = 0; ysi < YSPLIT; ++ysi)
                m = fminf(m, rowmin[(size_t)ysi*NPTS + row]);
            float d2 = fmaxf(m + cadT[row].w, 0.f);
            local += sqrt((double)d2);
        }
        red[tid] = local;
        __syncthreads();
        for (int s = 128; s > 0; s >>= 1) {
            if (tid < s) red[tid] += red[tid + s];
            __syncthreads();
        }
        if (tid == 0) atomicAdd((double*)((char*)ws + WS_SUMS_OFF) + p*2 + 0, red[0]);
    } else {
        int q = b - 32;
        int p = q >> 3, seg = q & 7;
        const float* colmin = (const float*)((const char*)ws + WS_COLMIN_OFF) + (size_t)p*XT*NPTS;
        for (int k = 0; k < 4; ++k) {
            int y = seg*1024 + k*256 + tid;
            float m = INFINITY;
            #pragma unroll
            for (int xt = 0; xt < XT; ++xt)
                m = fminf(m, colmin[(size_t)xt*NPTS + y]);
            float d2 = fmaxf(m, 0.f);
            local += sqrt((double)d2);
        }
        red[tid] = local;
        __syncthreads();
        for (int s = 128; s > 0; s >>= 1) {
            if (tid < s) red[tid] += red[tid + s];
            __syncthreads();
        }
        if (tid == 0) atomicAdd((double*)((char*)ws + WS_SUMS_OFF) + p*2 + 1, red[0]);
    }
}

__global__ void k_final(const float* __restrict__ pw,
                        const float* __restrict__ rtk,
                        const float* __restrict__ ja,
                        const float* __restrict__ ws,
                        float* __restrict__ out) {
    const double* sums = (const double*)((const char*)ws + WS_SUMS_OFF);
    double eners[NPARTS];
    for (int p = 0; p < NPARTS; ++p)
        eners[p] = 5.0 * ((sums[p*2+0] + sums[p*2+1]) / (double)NPTS);

    double mn = eners[0], mx = eners[0];
    for (int p = 1; p < NPARTS; ++p) { mn = fmin(mn, eners[p]); mx = fmax(mx, eners[p]); }
    double et[NPARTS], etmax = -1e300;
    for (int p = 0; p < NPARTS; ++p) { et[p] = (eners[p] - mn) / (mx - mn + 1e-8); etmax = fmax(etmax, et[p]); }
    double ex[NPARTS], se = 0.0;
    for (int p = 0; p < NPARTS; ++p) { ex[p] = exp(et[p] - etmax); se += ex[p]; }

    double ep[NPARTS], all_obj = 0.0, epmax = -1e300;
    for (int p = 0; p < NPARTS; ++p) {
        double sm = ex[p] / se;
        ep[p] = (double)pw[p] * sm * eners[p];
        all_obj += sm * eners[p];
        epmax = fmax(epmax, ep[p]);
    }

    double distances = sums[8] / (double)(NPARTS * NPTS);

    // Tj_q = rt_k[0] @ T[0] @ ja[0,0];  Tj1_q[j] = rt_k[j+1] @ T[j+1] @ ja[j,1]
    double v[4], Tj[4], ss = 0.0;
    for (int i = 0; i < 4; ++i) {
        v[i] = 0.0;
        for (int k = 0; k < 4; ++k) v[i] += (double)ws[0*16 + i*4 + k] * (double)ja[0*8 + 0*4 + k];
    }
    for (int i = 0; i < 4; ++i) {
        Tj[i] = 0.0;
        for (int k = 0; k < 4; ++k) Tj[i] += (double)rtk[0*16 + i*4 + k] * v[k];
    }
    for (int q = 1; q < NPARTS; ++q) {
        double vv[4], u[4];
        for (int i = 0; i < 4; ++i) {
            vv[i] = 0.0;
            for (int k = 0; k < 4; ++k) vv[i] += (double)ws[q*16 + i*4 + k] * (double)ja[(q-1)*8 + 4 + k];
        }
        for (int i = 0; i < 4; ++i) {
            u[i] = 0.0;
            for (int k = 0; k < 4; ++k) u[i] += (double)rtk[q*16 + i*4 + k] * vv[k];
        }
        for (int i = 0; i < 3; ++i) { double dd = Tj[i] - u[i]; ss += dd * dd; }
    }
    double nrm = sqrt(ss) / (double)NPARTS;
    double e_kin = log(0.1 * nrm + 1.0) + distances;
    double ekt = epmax * e_kin;
    all_obj += ekt;

    out[0] = (float)all_obj;
    for (int p = 0; p < NPARTS; ++p) out[1 + p] = (float)ep[p];
    out[5] = (float)ekt;
}

extern "C" void kernel_launch(void* const* d_in, const int* in_sizes, int n_in,
                              void* d_out, int out_size, void* d_ws, size_t ws_size,
                              hipStream_t stream) {
    const float* cam  = (const float*)d_in[0];
    const float* cad  = (const float*)d_in[1];
    const float* pw   = (const float*)d_in[2];
    const float* rq   = (const float*)d_in[3];
    const float* tras = (const float*)d_in[4];
    const float* rtk  = (const float*)d_in[5];
    const float* ja   = (const float*)d_in[6];
    float* out = (float*)d_out;
    float* ws  = (float*)d_ws;

    hipMemsetAsync((char*)ws + WS_SUMS_OFF, 0, 80, stream);
    hipLaunchKernelGGL(k_setup,   dim3(1),    dim3(256), 0, stream, rq, tras, ws, out);
    hipLaunchKernelGGL(k_pre,     dim3(128),  dim3(256), 0, stream, cam, cad, ws);
    hipLaunchKernelGGL(k_chamfer, dim3(2048), dim3(256), 0, stream, ws);
    hipLaunchKernelGGL(k_reduce,  dim3(64),   dim3(256), 0, stream, ws);
    hipLaunchKernelGGL(k_final,   dim3(1),    dim3(1),   0, stream, pw, rtk, ja, ws, out);
}